// Round 11
// baseline (436.498 us; speedup 1.0000x reference)
//
#include <hip/hip_runtime.h>
#include <hip/hip_bf16.h>

// MessagePassingLayer: N=50000, E=800000, F=H=128.
// out = swish([nodes | segsum(swish([n[s]|n[r]|e]@Wm1+bm1)@Wm2+bm2)]@Wu1+bu1)@Wu2+bu2
//
// Restructures:
//  (1) msg pre-act = Pa[snd] + Pb[rcv] + edges@Wm1c, P = nodes@[Wm1a|Wm1b] (+bm1 in Pa), bf16.
//  (2) Wm2 commutes with segsum: edge kernel reduces S = segsum(swish(x)), deg = segcount;
//      node_out uses Wc = Wm2@Wu1b, bvec = bm2@Wu1b.
//  (3) Edge kernel v11 = v10 dataflow at 8 waves/512 threads:
//      128 edges/block, NON-persistent in-order grid 6250 (co-running blocks share the P
//      window in L3), coalesced 16-lane full-row Psum gather into swizzled PsT, per-wave
//      16 up-front NT edge loads, GEMM1-T (wave tile 128 outcols x 16 edges, acc[8]=32 AGPR)
//      from L1-hot global weights, MFMA one-hot segmented reduce (runstart lo/hi),
//      interior-run plain stores + boundary atomics, XCD-chunked bijective remap.
//      __launch_bounds__(512,4): ~92 unified regs/wave <= 128 cap -> 2 blocks/CU =
//      16 waves/CU (v10 was stuck at 12: acc[8][2]=64 AGPR + 76 VGPR = 140 > 128 bucket).
//  (4) zero_kernel instead of in-graph hipMemsetAsync (rocclr fill ran at 104 GB/s in-graph).

typedef __bf16 bf16_t;
typedef __bf16 bf16x8 __attribute__((ext_vector_type(8)));
typedef float f32x4 __attribute__((ext_vector_type(4)));

#define MFMA16(a, b, c) __builtin_amdgcn_mfma_f32_16x16x32_bf16((a), (b), (c), 0, 0, 0)

__device__ __forceinline__ bf16x8 cvt_bf16x8(f32x4 lo, f32x4 hi) {
  bf16x8 r;
  r[0] = (bf16_t)lo[0]; r[1] = (bf16_t)lo[1]; r[2] = (bf16_t)lo[2]; r[3] = (bf16_t)lo[3];
  r[4] = (bf16_t)hi[0]; r[5] = (bf16_t)hi[1]; r[6] = (bf16_t)hi[2]; r[7] = (bf16_t)hi[3];
  return r;
}

__device__ __forceinline__ float swishf(float x) { return x / (1.0f + __expf(-x)); }

// PsT element index for (col, e): 128 cols x 128 edges bf16, XOR-swizzled so that
// (a) reduce b128 reads (16 lanes = 16 cols, same edge chunk) and
// (b) gather/epilogue scalar ops (fixed edge, col scatter) both spread banks.
__device__ __forceinline__ int pst_idx(int col, int e) {
  const int unit = (e >> 3) ^ (col & 7) ^ ((col >> 3) & 7);
  return col * 128 + unit * 8 + (e & 7);
}

// ---------------- zero workspace (S + deg contiguous) ----------------
__global__ __launch_bounds__(256) void zero_kernel(float* __restrict__ p, const long nvec) {
  const long t0 = (long)blockIdx.x * blockDim.x + threadIdx.x;
  const long stride = (long)gridDim.x * blockDim.x;
  for (long i = t0; i < nvec; i += stride) *(f32x4*)(p + i * 4) = f32x4{0.f, 0.f, 0.f, 0.f};
}

// ---------------- weight prep ----------------
__global__ void prep_kernel(const float* __restrict__ Wm1, const float* __restrict__ Wm2,
                            const float* __restrict__ Wu1, const float* __restrict__ Wu2,
                            const float* __restrict__ bm2,
                            bf16_t* __restrict__ WmabT, bf16_t* __restrict__ Wm1cT,
                            bf16_t* __restrict__ Wu1aT, bf16_t* __restrict__ WcT,
                            bf16_t* __restrict__ Wu2T, float* __restrict__ bvec) {
  const int t0 = blockIdx.x * blockDim.x + threadIdx.x;
  const int stride = gridDim.x * blockDim.x;
  for (int i = t0; i < 256 * 128; i += stride) {
    const int n = i >> 7, k = i & 127;
    const float v = (n < 128) ? Wm1[k * 128 + n] : Wm1[(128 + k) * 128 + (n - 128)];
    WmabT[i] = (bf16_t)v;
  }
  for (int i = t0; i < 128 * 128; i += stride) {
    const int n = i >> 7, k = i & 127;
    Wm1cT[i] = (bf16_t)Wm1[(256 + k) * 128 + n];
    Wu1aT[i] = (bf16_t)Wu1[k * 128 + n];
    Wu2T[i]  = (bf16_t)Wu2[k * 128 + n];
  }
  // Wc = Wm2 @ Wu1b, transposed: WcT[c*128+r] = sum_k Wm2[r,k]*Wu1[128+k,c]
  for (int i = t0; i < 128 * 128; i += stride) {
    const int r = i >> 7, c = i & 127;
    float acc = 0.f;
    for (int k = 0; k < 128; ++k) acc += Wm2[r * 128 + k] * Wu1[(128 + k) * 128 + c];
    WcT[c * 128 + r] = (bf16_t)acc;
  }
  if (t0 < 128) {
    float acc = 0.f;
    for (int k = 0; k < 128; ++k) acc += bm2[k] * Wu1[(128 + k) * 128 + t0];
    bvec[t0] = acc;
  }
}

// ---------------- node_pre: P = [nodes@Wm1a + bm1 | nodes@Wm1b] (bf16) ----------------
__global__ __launch_bounds__(256) void node_pre_kernel(const float* __restrict__ nodes,
                                                       const bf16_t* __restrict__ WmabT,
                                                       const float* __restrict__ bm1,
                                                       bf16_t* __restrict__ P, const int nN) {
  const int tid = threadIdx.x;
  const int l = tid & 63, w = tid >> 6;
  const int wr = w >> 1, wc = w & 1;
  const int lr = l & 15, lk = l >> 4;
  const int half = blockIdx.y;
  const int r0 = blockIdx.x * 128 + wr * 64;
  const bf16_t* WT = WmabT + half * (128 * 128);

  f32x4 acc[4][4] = {};
#pragma unroll
  for (int ks = 0; ks < 4; ++ks) {
    bf16x8 a[4], b[4];
#pragma unroll
    for (int m = 0; m < 4; ++m) {
      int r = r0 + m * 16 + lr;
      if (r >= nN) r = nN - 1;
      const float* p = nodes + (long)r * 128 + ks * 32 + lk * 8;
      a[m] = cvt_bf16x8(*(const f32x4*)p, *(const f32x4*)(p + 4));
    }
#pragma unroll
    for (int n = 0; n < 4; ++n)
      b[n] = *(const bf16x8*)(WT + (wc * 64 + n * 16 + lr) * 128 + ks * 32 + lk * 8);
#pragma unroll
    for (int m = 0; m < 4; ++m)
#pragma unroll
      for (int n = 0; n < 4; ++n)
        acc[m][n] = MFMA16(a[m], b[n], acc[m][n]);
  }
#pragma unroll
  for (int m = 0; m < 4; ++m)
#pragma unroll
    for (int n = 0; n < 4; ++n)
#pragma unroll
      for (int j = 0; j < 4; ++j) {
        const int r = r0 + m * 16 + lk * 4 + j;
        const int c = wc * 64 + n * 16 + lr;
        const float bias = (half == 0) ? bm1[c] : 0.f;  // fold bm1 into Pa
        if (r < nN) P[(long)r * 256 + half * 128 + c] = (bf16_t)(acc[m][n][j] + bias);
      }
}

// ---------------- edge kernel v11: 512 thr / 8 waves, 128 edges/block ----------------
__global__ __launch_bounds__(512, 4) void edge_kernel(
    const float* __restrict__ edges, const int* __restrict__ senders,
    const int* __restrict__ receivers, const bf16_t* __restrict__ P,
    const bf16_t* __restrict__ Wm1cT, float* __restrict__ S, float* __restrict__ deg,
    const int nwg) {
  __shared__ bf16_t PsT[128 * 128];          // [col][edge], swizzled (32 KB)
  __shared__ int runidL[128];
  __shared__ int runstartL[129];
  __shared__ unsigned long long maskL[2];
  __shared__ int nrunsL;
  const int tid = threadIdx.x;
  const int lane = tid & 63, w = tid >> 6;   // w in 0..7
  const int lr = lane & 15, lk = lane >> 4;

  // XCD-chunked bijective remap (contiguous edge ranges -> one XCD: S-line locality)
  int bid = blockIdx.x;
  {
    const int q = nwg >> 3, r = nwg & 7;
    const int xcd = bid & 7, idx = bid >> 3;
    bid = (xcd < r ? xcd * (q + 1) : r * (q + 1) + (xcd - r) * q) + idx;
  }
  const long e0 = (long)bid * 128;
  const int eg = w * 16 + lr;  // this lane's edge within the tile (0..127)

  // ---- issue this wave's 8 edge B-operand NT loads up-front ----
  f32x4 Bf[4][2];
#pragma unroll
  for (int kc = 0; kc < 4; ++kc) {
    const f32x4* p = (const f32x4*)(edges + (e0 + eg) * 128 + kc * 32 + lk * 8);
    Bf[kc][0] = __builtin_nontemporal_load(p);
    Bf[kc][1] = __builtin_nontemporal_load(p + 1);
  }

  // ---- run-structure phase 1: heads + per-wave ballot (waves 0,1 handle 128 edges) ----
  int head = 0, myrcv = 0;
  if (tid < 128) {
    myrcv = receivers[e0 + tid];
    const int prev = (tid == 0) ? -1 : receivers[e0 + tid - 1];
    head = (myrcv != prev) ? 1 : 0;
  }
  {
    const unsigned long long mask = __ballot(tid < 128 ? head : 0);
    if (tid < 128 && (tid & 63) == 0) maskL[tid >> 6] = mask;
  }

  // ---- gather Psum = Pa[snd]+Pb[rcv] into PsT (transposed, swizzled); bm1 already in Pa ----
  // chunk c: 16 consecutive lanes cover one 256-B P row (coalesced reads).
#pragma unroll
  for (int i = 0; i < 4; ++i) {
    const int c = tid + i * 512;
    const int row = c >> 4, k = c & 15;  // row = edge, cols k*8..k*8+7
    const int sn = senders[e0 + row];
    const int rn = receivers[e0 + row];
    const bf16x8 pa = *(const bf16x8*)(P + (long)sn * 256 + k * 8);
    const bf16x8 pb = *(const bf16x8*)(P + (long)rn * 256 + 128 + k * 8);
#pragma unroll
    for (int j = 0; j < 8; ++j) {
      const float v = (float)pa[j] + (float)pb[j];
      PsT[pst_idx(k * 8 + j, row)] = (bf16_t)v;
    }
  }

  // ---- GEMM1-T: X^T[col][edge] = Wm1c^T @ edges^T (A from global L1-hot, B in regs) ----
  // Wave tile: 128 outcols x 16 edges. acc[8] = 32 AGPR.
  f32x4 acc[8] = {};
#pragma unroll
  for (int kc = 0; kc < 4; ++kc) {
    const bf16x8 bb = cvt_bf16x8(Bf[kc][0], Bf[kc][1]);
#pragma unroll
    for (int m = 0; m < 8; ++m) {
      const bf16x8 aW = *(const bf16x8*)(Wm1cT + (m * 16 + lr) * 128 + kc * 32 + lk * 8);
      acc[m] = MFMA16(aW, bb, acc[m]);
    }
  }
  __syncthreads();  // PsT gather + ballot masks complete

  // ---- run-structure phase 2: global prefix, runid/runstart ----
  if (tid < 128) {
    const unsigned long long m0 = maskL[0], m1 = maskL[1];
    const int nruns = __popcll(m0) + __popcll(m1);
    if (tid == 0) { nrunsL = nruns; runstartL[nruns] = 128; }
    if (head) {
      const unsigned long long mymask = (tid < 64) ? m0 : m1;
      int pre = __popcll(mymask & ((1ull << (tid & 63)) - 1));
      if (tid >= 64) pre += __popcll(m0);
      runidL[pre] = myrcv;
      runstartL[pre] = tid;
    }
  }

  // ---- epilogue: H' = swish(acc + Psum), in place in PsT ----
  // D-frag: col(lane&15) -> edge eg, row((lane>>4)*4+j) -> outcol m*16+lk*4+j.
#pragma unroll
  for (int m = 0; m < 8; ++m)
#pragma unroll
    for (int j = 0; j < 4; ++j) {
      const int outcol = m * 16 + lk * 4 + j;
      const int idx = pst_idx(outcol, eg);
      const float x = acc[m][j] + (float)PsT[idx];
      PsT[idx] = (bf16_t)swishf(x);
    }
  __syncthreads();  // H' + run structure ready

  // ---- segmented reduce via MFMA: S^T[col][run] = H'^T @ R^T (one-hot from runstart lo/hi) ----
  const int nruns = nrunsL;
  for (int nt = 0; nt * 16 < nruns; ++nt) {
    const int myrun = nt * 16 + lr;
    int lo = 128, hi = 128, myid = -1;
    if (myrun < nruns) {
      lo = runstartL[myrun];
      hi = runstartL[myrun + 1];
      myid = runidL[myrun];
    }
    f32x4 accS = {};
#pragma unroll
    for (int kc = 0; kc < 4; ++kc) {
      bf16x8 bR;
#pragma unroll
      for (int j = 0; j < 8; ++j) {
        const int e = kc * 32 + lk * 8 + j;
        bR[j] = (e >= lo && e < hi) ? (bf16_t)1.0f : (bf16_t)0.0f;
      }
      const int col = w * 16 + lr;
      const int unit = (kc * 4 + lk) ^ (col & 7) ^ ((col >> 3) & 7);
      const bf16x8 aH = *(const bf16x8*)&PsT[col * 128 + unit * 8];
      accS = MFMA16(aH, bR, accS);
    }
    // D: col(lane&15)=run, row=(lane>>4)*4+j -> outcol w*16+lk*4+j. Interior run -> vector store.
    if (myrun < nruns) {
      const long base = (long)myid * 128;
      const int col0 = w * 16 + lk * 4;
      if (myrun == 0 || myrun == nruns - 1) {
#pragma unroll
        for (int j = 0; j < 4; ++j) unsafeAtomicAdd(&S[base + col0 + j], accS[j]);
      } else {
        *(f32x4*)(S + base + col0) = accS;
      }
    }
  }

  // deg: run lengths
  if (tid < nruns) {
    const float len = (float)(runstartL[tid + 1] - runstartL[tid]);
    const int node = runidL[tid];
    if (tid == 0 || tid == nruns - 1) unsafeAtomicAdd(&deg[node], len);
    else deg[node] = len;
  }
}

// ---------------- node_out: swish(nodes@Wu1a + S@Wc + deg*bvec + bu1) @ Wu2 + bu2 ----------------
__global__ __launch_bounds__(256) void node_out_kernel(
    const float* __restrict__ nodes, const float* __restrict__ S,
    const float* __restrict__ deg, const float* __restrict__ bvec,
    const float* __restrict__ bu1, const float* __restrict__ bu2,
    const bf16_t* __restrict__ Wu1aT, const bf16_t* __restrict__ WcT,
    const bf16_t* __restrict__ Wu2T, float* __restrict__ out, const int nN) {
  __shared__ bf16_t Hs[128 * 128];
  const int tid = threadIdx.x;
  const int l = tid & 63, w = tid >> 6;
  const int wr = w >> 1, wc = w & 1;
  const int lr = l & 15, lk = l >> 4;
  const int r0 = blockIdx.x * 128;

  f32x4 acc[4][4] = {};
#pragma unroll
  for (int src = 0; src < 2; ++src) {
    const float* X = src ? S : nodes;
    const bf16_t* WT = src ? WcT : Wu1aT;
#pragma unroll
    for (int ks = 0; ks < 4; ++ks) {
      bf16x8 a[4], b[4];
#pragma unroll
      for (int m = 0; m < 4; ++m) {
        int r = r0 + wr * 64 + m * 16 + lr;
        if (r >= nN) r = nN - 1;
        const float* p = X + (long)r * 128 + ks * 32 + lk * 8;
        a[m] = cvt_bf16x8(*(const f32x4*)p, *(const f32x4*)(p + 4));
      }
#pragma unroll
      for (int n = 0; n < 4; ++n)
        b[n] = *(const bf16x8*)(WT + (wc * 64 + n * 16 + lr) * 128 + ks * 32 + lk * 8);
#pragma unroll
      for (int m = 0; m < 4; ++m)
#pragma unroll
        for (int n = 0; n < 4; ++n)
          acc[m][n] = MFMA16(a[m], b[n], acc[m][n]);
    }
  }

#pragma unroll
  for (int m = 0; m < 4; ++m)
#pragma unroll
    for (int n = 0; n < 4; ++n)
#pragma unroll
      for (int j = 0; j < 4; ++j) {
        const int row = wr * 64 + m * 16 + lk * 4 + j;
        const int gr = r0 + row;
        const int col = wc * 64 + n * 16 + lr;
        const float dg = (gr < nN) ? deg[gr] : 0.f;
        const float x = acc[m][n][j] + bu1[col] + dg * bvec[col];
        Hs[row * 128 + (col ^ ((row & 7) << 3))] = (bf16_t)swishf(x);
      }
  __syncthreads();

  f32x4 acc2[4][4] = {};
#pragma unroll
  for (int ks = 0; ks < 4; ++ks) {
    bf16x8 a[4], b[4];
#pragma unroll
    for (int m = 0; m < 4; ++m) {
      const int r = wr * 64 + m * 16 + lr;
      a[m] = *(const bf16x8*)&Hs[r * 128 + ((ks * 32 + lk * 8) ^ ((r & 7) << 3))];
    }
#pragma unroll
    for (int n = 0; n < 4; ++n)
      b[n] = *(const bf16x8*)(Wu2T + (wc * 64 + n * 16 + lr) * 128 + ks * 32 + lk * 8);
#pragma unroll
    for (int m = 0; m < 4; ++m)
#pragma unroll
      for (int n = 0; n < 4; ++n)
        acc2[m][n] = MFMA16(a[m], b[n], acc2[m][n]);
  }

#pragma unroll
  for (int m = 0; m < 4; ++m)
#pragma unroll
    for (int n = 0; n < 4; ++n)
#pragma unroll
      for (int j = 0; j < 4; ++j) {
        const int row = r0 + wr * 64 + m * 16 + lk * 4 + j;
        const int col = wc * 64 + n * 16 + lr;
        if (row < nN) out[(long)row * 128 + col] = acc2[m][n][j] + bu2[col];
      }
}

extern "C" void kernel_launch(void* const* d_in, const int* in_sizes, int n_in,
                              void* d_out, int out_size, void* d_ws, size_t ws_size,
                              hipStream_t stream) {
  const float* nodes = (const float*)d_in[0];
  const float* edges = (const float*)d_in[1];
  const int* senders = (const int*)d_in[2];
  const int* receivers = (const int*)d_in[3];
  const float* Wm1 = (const float*)d_in[4];
  const float* bm1 = (const float*)d_in[5];
  const float* Wm2 = (const float*)d_in[6];
  const float* bm2 = (const float*)d_in[7];
  const float* Wu1 = (const float*)d_in[8];
  const float* bu1 = (const float*)d_in[9];
  const float* Wu2 = (const float*)d_in[10];
  const float* bu2 = (const float*)d_in[11];
  const int nN = in_sizes[0] / 128;  // 50000
  const int nE = in_sizes[1] / 128;  // 800000

  // workspace (~51.6 MB): P (bf16) | S (f32) | deg | weights
  char* ws = (char*)d_ws;
  bf16_t* P = (bf16_t*)ws;
  float* S = (float*)(ws + (size_t)nN * 256 * 2);
  float* deg = S + (size_t)nN * 128;
  bf16_t* WmabT = (bf16_t*)(deg + nN);
  bf16_t* Wm1cT = WmabT + 256 * 128;
  bf16_t* Wu1aT = Wm1cT + 128 * 128;
  bf16_t* WcT = Wu1aT + 128 * 128;
  bf16_t* Wu2T = WcT + 128 * 128;
  float* bvec = (float*)(Wu2T + 128 * 128);

  // zero S + deg (contiguous, nN*129 floats, divisible by 4)
  hipLaunchKernelGGL(zero_kernel, dim3(1024), dim3(256), 0, stream,
                     S, (long)nN * 129 / 4);
  hipLaunchKernelGGL(prep_kernel, dim3(128), dim3(256), 0, stream,
                     Wm1, Wm2, Wu1, Wu2, bm2, WmabT, Wm1cT, Wu1aT, WcT, Wu2T, bvec);
  hipLaunchKernelGGL(node_pre_kernel, dim3((nN + 127) / 128, 2), dim3(256), 0, stream,
                     nodes, WmabT, bm1, P, nN);
  hipLaunchKernelGGL(edge_kernel, dim3(nE / 128), dim3(512), 0, stream,
                     edges, senders, receivers, P, Wm1cT, S, deg, nE / 128);
  hipLaunchKernelGGL(node_out_kernel, dim3((nN + 127) / 128), dim3(256), 0, stream,
                     nodes, S, deg, bvec, bu1, bu2, Wu1aT, WcT, Wu2T, (float*)d_out, nN);
}

// Round 12
// 287.084 us; speedup vs baseline: 1.5205x; 1.5205x over previous
//
#include <hip/hip_runtime.h>
#include <hip/hip_bf16.h>

// MessagePassingLayer: N=50000, E=800000, F=H=128.
// out = swish([nodes | segsum(swish([n[s]|n[r]|e]@Wm1+bm1)@Wm2+bm2)]@Wu1+bu1)@Wu2+bu2
//
// Restructures:
//  (1) msg pre-act = Pa[snd] + Pb[rcv] + edges@Wm1c, with P = nodes@[Wm1a|Wm1b] (+bm1 folded
//      into Pa) precomputed in bf16.
//  (2) Wm2 commutes with segsum: edge kernel reduces S = segsum(swish(x)), deg = segcount;
//      node_out uses Wc = Wm2@Wu1b, bvec = bm2@Wu1b.
//  (3) Edge kernel v12 == v7 (best measured: ~207us inferred from R7's 287 total):
//      PERSISTENT blocks (grid=768 = 3/CU, LDS 49.7KB):
//      - Wm1c^T staged once per block into LDS (row-XOR chunk swizzle, conflict-free b128)
//      - Psum gathered DIRECTLY into registers in the MFMA D-frag layout (16 x 8B loads/lane)
//      - per-tile: NT edge loads -> GEMM1-T (acc=0) -> +psum,swish -> PsT -> MFMA one-hot
//        segmented reduce (runstart ranges), interior runs plain f32x4 stores, boundary
//        atomics. XCD-chunked contiguous tile ranges. NO cross-tile software pipeline
//        (v8 lesson: the Bf double-buffer rotation cost 120us via register pressure).
//  (4) zero_kernel for S+deg init (retained from v8; neutral vs hipMemsetAsync).

typedef __bf16 bf16_t;
typedef __bf16 bf16x8 __attribute__((ext_vector_type(8)));
typedef __bf16 bf16x4 __attribute__((ext_vector_type(4)));
typedef float f32x4 __attribute__((ext_vector_type(4)));

#define MFMA16(a, b, c) __builtin_amdgcn_mfma_f32_16x16x32_bf16((a), (b), (c), 0, 0, 0)

__device__ __forceinline__ bf16x8 cvt_bf16x8(f32x4 lo, f32x4 hi) {
  bf16x8 r;
  r[0] = (bf16_t)lo[0]; r[1] = (bf16_t)lo[1]; r[2] = (bf16_t)lo[2]; r[3] = (bf16_t)lo[3];
  r[4] = (bf16_t)hi[0]; r[5] = (bf16_t)hi[1]; r[6] = (bf16_t)hi[2]; r[7] = (bf16_t)hi[3];
  return r;
}

__device__ __forceinline__ float swishf(float x) { return x / (1.0f + __expf(-x)); }

// PsT element index for (col, e): 128 cols x 64 edges bf16, XOR-swizzled.
__device__ __forceinline__ int pst_idx(int col, int e) {
  const int unit = (e >> 3) ^ (col & 7) ^ ((col >> 3) & 7);
  return col * 64 + unit * 8 + (e & 7);
}

// ---------------- zero workspace (S + deg contiguous) ----------------
__global__ __launch_bounds__(256) void zero_kernel(float* __restrict__ p, const long nvec) {
  const long t0 = (long)blockIdx.x * blockDim.x + threadIdx.x;
  const long stride = (long)gridDim.x * blockDim.x;
  for (long i = t0; i < nvec; i += stride) *(f32x4*)(p + i * 4) = f32x4{0.f, 0.f, 0.f, 0.f};
}

// ---------------- weight prep ----------------
__global__ void prep_kernel(const float* __restrict__ Wm1, const float* __restrict__ Wm2,
                            const float* __restrict__ Wu1, const float* __restrict__ Wu2,
                            const float* __restrict__ bm2,
                            bf16_t* __restrict__ WmabT, bf16_t* __restrict__ Wm1cT,
                            bf16_t* __restrict__ Wu1aT, bf16_t* __restrict__ WcT,
                            bf16_t* __restrict__ Wu2T, float* __restrict__ bvec) {
  const int t0 = blockIdx.x * blockDim.x + threadIdx.x;
  const int stride = gridDim.x * blockDim.x;
  for (int i = t0; i < 256 * 128; i += stride) {
    const int n = i >> 7, k = i & 127;
    const float v = (n < 128) ? Wm1[k * 128 + n] : Wm1[(128 + k) * 128 + (n - 128)];
    WmabT[i] = (bf16_t)v;
  }
  for (int i = t0; i < 128 * 128; i += stride) {
    const int n = i >> 7, k = i & 127;
    Wm1cT[i] = (bf16_t)Wm1[(256 + k) * 128 + n];
    Wu1aT[i] = (bf16_t)Wu1[k * 128 + n];
    Wu2T[i]  = (bf16_t)Wu2[k * 128 + n];
  }
  // Wc = Wm2 @ Wu1b, transposed: WcT[c*128+r] = sum_k Wm2[r,k]*Wu1[128+k,c]
  for (int i = t0; i < 128 * 128; i += stride) {
    const int r = i >> 7, c = i & 127;
    float acc = 0.f;
    for (int k = 0; k < 128; ++k) acc += Wm2[r * 128 + k] * Wu1[(128 + k) * 128 + c];
    WcT[c * 128 + r] = (bf16_t)acc;
  }
  if (t0 < 128) {
    float acc = 0.f;
    for (int k = 0; k < 128; ++k) acc += bm2[k] * Wu1[(128 + k) * 128 + t0];
    bvec[t0] = acc;
  }
}

// ---------------- node_pre: P = [nodes@Wm1a + bm1 | nodes@Wm1b] (bf16) ----------------
__global__ __launch_bounds__(256) void node_pre_kernel(const float* __restrict__ nodes,
                                                       const bf16_t* __restrict__ WmabT,
                                                       const float* __restrict__ bm1,
                                                       bf16_t* __restrict__ P, const int nN) {
  const int tid = threadIdx.x;
  const int l = tid & 63, w = tid >> 6;
  const int wr = w >> 1, wc = w & 1;
  const int lr = l & 15, lk = l >> 4;
  const int half = blockIdx.y;
  const int r0 = blockIdx.x * 128 + wr * 64;
  const bf16_t* WT = WmabT + half * (128 * 128);

  f32x4 acc[4][4] = {};
#pragma unroll
  for (int ks = 0; ks < 4; ++ks) {
    bf16x8 a[4], b[4];
#pragma unroll
    for (int m = 0; m < 4; ++m) {
      int r = r0 + m * 16 + lr;
      if (r >= nN) r = nN - 1;
      const float* p = nodes + (long)r * 128 + ks * 32 + lk * 8;
      a[m] = cvt_bf16x8(*(const f32x4*)p, *(const f32x4*)(p + 4));
    }
#pragma unroll
    for (int n = 0; n < 4; ++n)
      b[n] = *(const bf16x8*)(WT + (wc * 64 + n * 16 + lr) * 128 + ks * 32 + lk * 8);
#pragma unroll
    for (int m = 0; m < 4; ++m)
#pragma unroll
      for (int n = 0; n < 4; ++n)
        acc[m][n] = MFMA16(a[m], b[n], acc[m][n]);
  }
#pragma unroll
  for (int m = 0; m < 4; ++m)
#pragma unroll
    for (int n = 0; n < 4; ++n)
#pragma unroll
      for (int j = 0; j < 4; ++j) {
        const int r = r0 + m * 16 + lk * 4 + j;
        const int c = wc * 64 + n * 16 + lr;
        const float bias = (half == 0) ? bm1[c] : 0.f;  // fold bm1 into Pa
        if (r < nN) P[(long)r * 256 + half * 128 + c] = (bf16_t)(acc[m][n][j] + bias);
      }
}

// ---------------- edge kernel v12 (= v7): persistent, 64 edges/tile, 4 waves ----------------
__global__ __launch_bounds__(256, 3) void edge_kernel(
    const float* __restrict__ edges, const int* __restrict__ senders,
    const int* __restrict__ receivers, const bf16_t* __restrict__ P,
    const bf16_t* __restrict__ Wm1cT, float* __restrict__ S, float* __restrict__ deg,
    const int ntiles) {
  __shared__ bf16_t Ws[128 * 128];   // Wm1c^T staged, row-XOR chunk swizzle (32 KB)
  __shared__ bf16_t PsT[128 * 64];   // H'^T [col][edge], XOR-swizzled (16 KB)
  __shared__ int runidL[64];
  __shared__ int runstartL[65];
  __shared__ int nrunsL;
  const int tid = threadIdx.x;
  const int lane = tid & 63, w = tid >> 6;
  const int lr = lane & 15, lk = lane >> 4;

  // ---- stage Ws once per block: phys chunk = c ^ (row&15) (16B chunks) ----
#pragma unroll
  for (int i = 0; i < 8; ++i) {
    const int g = tid + i * 256;      // 0..2047
    const int r = g >> 4, c = g & 15;
    const bf16x8 v = *(const bf16x8*)(Wm1cT + r * 128 + c * 8);
    *(bf16x8*)&Ws[r * 128 + ((c ^ (r & 15)) * 8)] = v;
  }

  // ---- contiguous tile range per block, XCD-chunked (gridDim.x divisible by 8) ----
  const int nb = gridDim.x;
  const int cb = (blockIdx.x & 7) * (nb >> 3) + (blockIdx.x >> 3);
  const int q = ntiles / nb, r2 = ntiles % nb;
  const int tstart = cb * q + (cb < r2 ? cb : r2);
  const int tcnt = q + (cb < r2 ? 1 : 0);

  __syncthreads();  // Ws ready

  for (int ti = 0; ti < tcnt; ++ti) {
    const long e0 = (long)(tstart + ti) * 64;
    const int eg = w * 16 + lr;  // this lane's edge within the tile

    // own-edge indices, then all bulk loads issued up-front
    const int sn = senders[e0 + eg];
    const int rn = receivers[e0 + eg];

    f32x4 Bf[4][2];
#pragma unroll
    for (int kc = 0; kc < 4; ++kc) {
      const f32x4* p = (const f32x4*)(edges + (e0 + eg) * 128 + kc * 32 + lk * 8);
      Bf[kc][0] = __builtin_nontemporal_load(p);
      Bf[kc][1] = __builtin_nontemporal_load(p + 1);
    }
    // Psum direct to registers in D-frag layout: cols m*16 + lk*4 + j
    bf16x4 pa[8], pb[8];
#pragma unroll
    for (int m = 0; m < 8; ++m) {
      pa[m] = *(const bf16x4*)(P + (long)sn * 256 + m * 16 + lk * 4);
      pb[m] = *(const bf16x4*)(P + (long)rn * 256 + 128 + m * 16 + lk * 4);
    }

    // run structure: wave 0 only (wave-synchronous)
    if (w == 0) {
      const int myrcv = receivers[e0 + lane];
      const int prev = (lane == 0) ? -1 : receivers[e0 + lane - 1];
      const int head = (myrcv != prev) ? 1 : 0;
      const unsigned long long mask = __ballot(head);
      const int nruns = __popcll(mask);
      if (lane == 0) { nrunsL = nruns; runstartL[nruns] = 64; }
      if (head) {
        const int pre = __popcll(mask & ((1ull << lane) - 1));
        runidL[pre] = myrcv;
        runstartL[pre] = lane;
      }
    }

    // GEMM1-T: X^T = Wm1c^T @ edges^T, weights from LDS (swizzled b128 reads)
    f32x4 acc[8] = {};
#pragma unroll
    for (int kc = 0; kc < 4; ++kc) {
      const bf16x8 bb = cvt_bf16x8(Bf[kc][0], Bf[kc][1]);
#pragma unroll
      for (int m = 0; m < 8; ++m) {
        const bf16x8 aW = *(const bf16x8*)&Ws[(m * 16 + lr) * 128 + (((kc * 4 + lk) ^ lr) * 8)];
        acc[m] = MFMA16(aW, bb, acc[m]);
      }
    }

    // epilogue: H' = swish(acc + Pa[snd] + Pb[rcv]) -> PsT (scalar b16 scatter)
#pragma unroll
    for (int m = 0; m < 8; ++m)
#pragma unroll
      for (int j = 0; j < 4; ++j) {
        const int outcol = m * 16 + lk * 4 + j;
        const float x = acc[m][j] + (float)pa[m][j] + (float)pb[m][j];
        PsT[pst_idx(outcol, eg)] = (bf16_t)swishf(x);
      }
    __syncthreads();  // H' + run structure visible

    // segmented reduce via MFMA: S^T[col][run] = H'^T @ R^T, R from runstart ranges
    const int nruns = nrunsL;
    for (int nt = 0; nt * 16 < nruns; ++nt) {
      const int myrun = nt * 16 + lr;
      int lo = 64, hi = 64, myid = -1;
      if (myrun < nruns) {
        lo = runstartL[myrun];
        hi = runstartL[myrun + 1];
        myid = runidL[myrun];
      }
      f32x4 accS[2] = {};
#pragma unroll
      for (int kc = 0; kc < 2; ++kc) {
        bf16x8 bR;
#pragma unroll
        for (int j = 0; j < 8; ++j) {
          const int e = kc * 32 + lk * 8 + j;
          bR[j] = (e >= lo && e < hi) ? (bf16_t)1.0f : (bf16_t)0.0f;
        }
#pragma unroll
        for (int t = 0; t < 2; ++t) {
          const int col = (2 * w + t) * 16 + lr;
          const int unit = (kc * 4 + lk) ^ (col & 7) ^ ((col >> 3) & 7);
          const bf16x8 aH = *(const bf16x8*)&PsT[col * 64 + unit * 8];
          accS[t] = MFMA16(aH, bR, accS[t]);
        }
      }
      if (myrun < nruns) {
        const long base = (long)myid * 128;
        const bool boundary = (myrun == 0) || (myrun == nruns - 1);
#pragma unroll
        for (int t = 0; t < 2; ++t) {
          const int col0 = (2 * w + t) * 16 + lk * 4;
          if (boundary) {
#pragma unroll
            for (int j = 0; j < 4; ++j) unsafeAtomicAdd(&S[base + col0 + j], accS[t][j]);
          } else {
            *(f32x4*)(S + base + col0) = accS[t];
          }
        }
      }
    }

    // deg: run lengths (wave 0 lanes)
    if (tid < nruns) {
      const float len = (float)(runstartL[tid + 1] - runstartL[tid]);
      const int node = runidL[tid];
      if (tid == 0 || tid == nruns - 1) unsafeAtomicAdd(&deg[node], len);
      else deg[node] = len;
    }
    __syncthreads();  // protect PsT/run arrays before next tile overwrites
  }
}

// ---------------- node_out: swish(nodes@Wu1a + S@Wc + deg*bvec + bu1) @ Wu2 + bu2 ----------------
__global__ __launch_bounds__(256) void node_out_kernel(
    const float* __restrict__ nodes, const float* __restrict__ S,
    const float* __restrict__ deg, const float* __restrict__ bvec,
    const float* __restrict__ bu1, const float* __restrict__ bu2,
    const bf16_t* __restrict__ Wu1aT, const bf16_t* __restrict__ WcT,
    const bf16_t* __restrict__ Wu2T, float* __restrict__ out, const int nN) {
  __shared__ bf16_t Hs[128 * 128];
  const int tid = threadIdx.x;
  const int l = tid & 63, w = tid >> 6;
  const int wr = w >> 1, wc = w & 1;
  const int lr = l & 15, lk = l >> 4;
  const int r0 = blockIdx.x * 128;

  f32x4 acc[4][4] = {};
#pragma unroll
  for (int src = 0; src < 2; ++src) {
    const float* X = src ? S : nodes;
    const bf16_t* WT = src ? WcT : Wu1aT;
#pragma unroll
    for (int ks = 0; ks < 4; ++ks) {
      bf16x8 a[4], b[4];
#pragma unroll
      for (int m = 0; m < 4; ++m) {
        int r = r0 + wr * 64 + m * 16 + lr;
        if (r >= nN) r = nN - 1;
        const float* p = X + (long)r * 128 + ks * 32 + lk * 8;
        a[m] = cvt_bf16x8(*(const f32x4*)p, *(const f32x4*)(p + 4));
      }
#pragma unroll
      for (int n = 0; n < 4; ++n)
        b[n] = *(const bf16x8*)(WT + (wc * 64 + n * 16 + lr) * 128 + ks * 32 + lk * 8);
#pragma unroll
      for (int m = 0; m < 4; ++m)
#pragma unroll
        for (int n = 0; n < 4; ++n)
          acc[m][n] = MFMA16(a[m], b[n], acc[m][n]);
    }
  }

#pragma unroll
  for (int m = 0; m < 4; ++m)
#pragma unroll
    for (int n = 0; n < 4; ++n)
#pragma unroll
      for (int j = 0; j < 4; ++j) {
        const int row = wr * 64 + m * 16 + lk * 4 + j;
        const int gr = r0 + row;
        const int col = wc * 64 + n * 16 + lr;
        const float dg = (gr < nN) ? deg[gr] : 0.f;
        const float x = acc[m][n][j] + bu1[col] + dg * bvec[col];
        Hs[row * 128 + (col ^ ((row & 7) << 3))] = (bf16_t)swishf(x);
      }
  __syncthreads();

  f32x4 acc2[4][4] = {};
#pragma unroll
  for (int ks = 0; ks < 4; ++ks) {
    bf16x8 a[4], b[4];
#pragma unroll
    for (int m = 0; m < 4; ++m) {
      const int r = wr * 64 + m * 16 + lr;
      a[m] = *(const bf16x8*)&Hs[r * 128 + ((ks * 32 + lk * 8) ^ ((r & 7) << 3))];
    }
#pragma unroll
    for (int n = 0; n < 4; ++n)
      b[n] = *(const bf16x8*)(Wu2T + (wc * 64 + n * 16 + lr) * 128 + ks * 32 + lk * 8);
#pragma unroll
    for (int m = 0; m < 4; ++m)
#pragma unroll
      for (int n = 0; n < 4; ++n)
        acc2[m][n] = MFMA16(a[m], b[n], acc2[m][n]);
  }

#pragma unroll
  for (int m = 0; m < 4; ++m)
#pragma unroll
    for (int n = 0; n < 4; ++n)
#pragma unroll
      for (int j = 0; j < 4; ++j) {
        const int row = r0 + wr * 64 + m * 16 + lk * 4 + j;
        const int col = wc * 64 + n * 16 + lr;
        if (row < nN) out[(long)row * 128 + col] = acc2[m][n][j] + bu2[col];
      }
}

extern "C" void kernel_launch(void* const* d_in, const int* in_sizes, int n_in,
                              void* d_out, int out_size, void* d_ws, size_t ws_size,
                              hipStream_t stream) {
  const float* nodes = (const float*)d_in[0];
  const float* edges = (const float*)d_in[1];
  const int* senders = (const int*)d_in[2];
  const int* receivers = (const int*)d_in[3];
  const float* Wm1 = (const float*)d_in[4];
  const float* bm1 = (const float*)d_in[5];
  const float* Wm2 = (const float*)d_in[6];
  const float* bm2 = (const float*)d_in[7];
  const float* Wu1 = (const float*)d_in[8];
  const float* bu1 = (const float*)d_in[9];
  const float* Wu2 = (const float*)d_in[10];
  const float* bu2 = (const float*)d_in[11];
  const int nN = in_sizes[0] / 128;  // 50000
  const int nE = in_sizes[1] / 128;  // 800000

  // workspace (~51.6 MB): P (bf16) | S (f32) | deg | weights
  char* ws = (char*)d_ws;
  bf16_t* P = (bf16_t*)ws;
  float* S = (float*)(ws + (size_t)nN * 256 * 2);
  float* deg = S + (size_t)nN * 128;
  bf16_t* WmabT = (bf16_t*)(deg + nN);
  bf16_t* Wm1cT = WmabT + 256 * 128;
  bf16_t* Wu1aT = Wm1cT + 128 * 128;
  bf16_t* WcT = Wu1aT + 128 * 128;
  bf16_t* Wu2T = WcT + 128 * 128;
  float* bvec = (float*)(Wu2T + 128 * 128);

  // zero S + deg (contiguous, nN*129 floats, divisible by 4)
  hipLaunchKernelGGL(zero_kernel, dim3(1024), dim3(256), 0, stream,
                     S, (long)nN * 129 / 4);
  hipLaunchKernelGGL(prep_kernel, dim3(128), dim3(256), 0, stream,
                     Wm1, Wm2, Wu1, Wu2, bm2, WmabT, Wm1cT, Wu1aT, WcT, Wu2T, bvec);
  hipLaunchKernelGGL(node_pre_kernel, dim3((nN + 127) / 128, 2), dim3(256), 0, stream,
                     nodes, WmabT, bm1, P, nN);
  hipLaunchKernelGGL(edge_kernel, dim3(768), dim3(256), 0, stream,
                     edges, senders, receivers, P, Wm1cT, S, deg, nE / 64);
  hipLaunchKernelGGL(node_out_kernel, dim3((nN + 127) / 128), dim3(256), 0, stream,
                     nodes, S, deg, bvec, bu1, bu2, Wu1aT, WcT, Wu2T, (float*)d_out, nN);
}